// Round 6
// baseline (179.264 us; speedup 1.0000x reference)
//
#include <hip/hip_runtime.h>

// ---------------- types ----------------
typedef __bf16 bf16_8 __attribute__((ext_vector_type(8)));
typedef __bf16 bf16_4 __attribute__((ext_vector_type(4)));
typedef float  f32_4  __attribute__((ext_vector_type(4)));
typedef short  s16x4  __attribute__((ext_vector_type(4)));

typedef __attribute__((address_space(1))) const void* as1_cvp;
typedef __attribute__((address_space(3))) void*       as3_vp;

__device__ __forceinline__ void load16_to_lds(const void* g, void* l) {
    __builtin_amdgcn_global_load_lds((as1_cvp)g, (as3_vp)l, 16, 0, 0);
}

__device__ __forceinline__ f32_4 mfma16x16x16(bf16_4 a, bf16_4 b, f32_4 c) {
#if __has_builtin(__builtin_amdgcn_mfma_f32_16x16x16_bf16)
    return __builtin_amdgcn_mfma_f32_16x16x16_bf16(a, b, c, 0, 0, 0);
#else
    return __builtin_amdgcn_mfma_f32_16x16x16bf16_1k(
        __builtin_bit_cast(s16x4, a), __builtin_bit_cast(s16x4, b), c, 0, 0, 0);
#endif
}

// ---------------- fused fp32 -> bf16 convert (x | Wqkv | Wproj) ----------------
__global__ __launch_bounds__(256) void cvt_all(
    const float* __restrict__ a, const float* __restrict__ b,
    const float* __restrict__ c, __bf16* __restrict__ out,
    int na4, int nb4, int nc4)
{
    int i = blockIdx.x * 256 + threadIdx.x;
    if (i >= na4 + nb4 + nc4) return;
    float4 f;
    if (i < na4)            f = ((const float4*)a)[i];
    else if (i < na4 + nb4) f = ((const float4*)b)[i - na4];
    else                    f = ((const float4*)c)[i - na4 - nb4];
    bf16_4 v = { (__bf16)f.x, (__bf16)f.y, (__bf16)f.z, (__bf16)f.w };
    ((bf16_4*)out)[i] = v;
}

// ---------------- bf16 GEMM: C[M,N] = A[M,K] * B[N,K]^T + bias ----------------
#define BM 128

template<int OUT_BF16, int BN_>
__global__ __launch_bounds__(256) void gemm_bt(
    const __bf16* __restrict__ A,   // [M,K]
    const __bf16* __restrict__ B,   // [N,K]
    const float*  __restrict__ bias,// [N] or nullptr
    __bf16* __restrict__ Cb, float* __restrict__ Cf,
    int M, int N, int K)
{
    constexpr int NT   = BN_ / 32;
    constexpr int CSTR = BN_ + (OUT_BF16 ? 8 : 4);
    __shared__ __align__(16) char smem[35840];
    __bf16* As = (__bf16*)smem;          // [128][64]
    __bf16* Bs = As + 128 * 64;          // [BN_][64]

    const int tid  = threadIdx.x;
    const int wave = tid >> 6;
    const int lane = tid & 63;
    const int wm = wave >> 1, wn = wave & 1;
    const int quad = lane >> 4, l16 = lane & 15;
    const int bm = blockIdx.y * BM, bn = blockIdx.x * BN_;

    const int r0 = tid >> 3;
    const int ch = tid & 7;
    const int cs = (ch ^ (r0 & 7)) * 8;

    f32_4 acc[4][NT];
    #pragma unroll
    for (int i = 0; i < 4; ++i)
        #pragma unroll
        for (int j = 0; j < NT; ++j)
            acc[i][j] = f32_4{0.f, 0.f, 0.f, 0.f};

    for (int k0 = 0; k0 < K; k0 += 64) {
        __syncthreads();
        #pragma unroll
        for (int p = 0; p < 4; ++p) {
            int row = p * 32 + r0;
            load16_to_lds(A + (size_t)(bm + row) * K + k0 + cs,
                          &As[(p * 32 + wave * 8) * 64]);
        }
        #pragma unroll
        for (int p = 0; p < BN_ / 32; ++p) {
            int row = p * 32 + r0;
            load16_to_lds(B + (size_t)(bn + row) * K + k0 + cs,
                          &Bs[(p * 32 + wave * 8) * 64]);
        }
        __syncthreads();

        #pragma unroll
        for (int h = 0; h < 2; ++h) {
            const int sl = ((quad + h * 4) ^ (l16 & 7)) * 8;
            bf16_8 af[4], bfr[NT];
            #pragma unroll
            for (int mt = 0; mt < 4; ++mt)
                af[mt] = *(const bf16_8*)&As[(wm * 64 + mt * 16 + l16) * 64 + sl];
            #pragma unroll
            for (int nt = 0; nt < NT; ++nt)
                bfr[nt] = *(const bf16_8*)&Bs[(wn * (BN_/2) + nt * 16 + l16) * 64 + sl];
            #pragma unroll
            for (int mt = 0; mt < 4; ++mt)
                #pragma unroll
                for (int nt = 0; nt < NT; ++nt)
                    acc[mt][nt] = __builtin_amdgcn_mfma_f32_16x16x32_bf16(
                        af[mt], bfr[nt], acc[mt][nt], 0, 0, 0);
        }
    }

    __syncthreads();

    if (OUT_BF16) {
        __bf16* Cs = (__bf16*)smem;
        #pragma unroll
        for (int mt = 0; mt < 4; ++mt)
            #pragma unroll
            for (int nt = 0; nt < NT; ++nt) {
                int col = wn * (BN_/2) + nt * 16 + l16;
                float bv = bias ? bias[bn + col] : 0.f;
                #pragma unroll
                for (int r = 0; r < 4; ++r)
                    Cs[(wm * 64 + mt * 16 + quad * 4 + r) * CSTR + col] =
                        (__bf16)(acc[mt][nt][r] + bv);
            }
        __syncthreads();
        const int rr = tid >> 4, cc = (tid & 15) * 8;
        #pragma unroll
        for (int p = 0; p < 8; ++p) {
            int row = p * 16 + rr;
            bf16_8 v = *(const bf16_8*)&Cs[row * CSTR + cc];
            *(bf16_8*)(Cb + (size_t)(bm + row) * N + bn + cc) = v;
        }
    } else {
        float* Cs = (float*)smem;
        #pragma unroll
        for (int mt = 0; mt < 4; ++mt)
            #pragma unroll
            for (int nt = 0; nt < NT; ++nt) {
                int col = wn * (BN_/2) + nt * 16 + l16;
                float bv = bias ? bias[bn + col] : 0.f;
                #pragma unroll
                for (int r = 0; r < 4; ++r)
                    Cs[(wm * 64 + mt * 16 + quad * 4 + r) * CSTR + col] =
                        acc[mt][nt][r] + bv;
            }
        __syncthreads();
        const int rr = tid >> 4, cc = (tid & 15) * 4;
        #pragma unroll
        for (int p = 0; p < 8; ++p) {
            int row = p * 16 + rr;
            float4 v = *(const float4*)&Cs[row * CSTR + cc];
            *(float4*)(Cf + (size_t)(bm + row) * N + bn + cc) = v;
        }
    }
}

// ---------------- causal flash attention v6 ----------------
// Transposed-score formulation: S^T = MFMA(A=K, B=Q) puts P^T in C/D layout =
// EXACTLY the B-fragment layout of mfma_16x16x16 -> PV (O^T = V^T x P^T) uses
// P straight from registers: NO P LDS roundtrip (was 16 writes + 2 reads/iter).
// 8 waves/block: wq=wave&3 owns 32 q-rows (2 m-frags), wg=wave>>2 splits keys.
// K staged via swizzled global_load_lds (dbuf); V transposed into swizzled Vt.
// Grid 512 (1 q-tile/block, LPT: heavy tiles first), 2 blocks/CU.
__global__ __launch_bounds__(512, 4) void attn_kernel(
    const __bf16* __restrict__ qkv, __bf16* __restrict__ out)
{
    constexpr int T = 2048;
    __shared__ __align__(16) char pool[35328];
    __bf16* Ks = (__bf16*)pool;             // [2][64*64] chunk-swizzled
    __bf16* Vt = (__bf16*)(pool + 16384);   // [2][64*64] transposed+swizzled
    float*  Om = (float*)pool;              // alias: [4][32][68] (34816 B)
    float*  Lm = (float*)(pool + 34816);    // [4][32]

    const int tid  = threadIdx.x;
    const int wave = tid >> 6;
    const int lane = tid & 63;
    const int wg = wave >> 2, wq = wave & 3;
    const int quad = lane >> 4, l16 = lane & 15;

    // LPT grid: heavy tiles (large z) dispatch first; 4 bh per XCD
    const int fid = blockIdx.x;             // 0..511
    const int xcd = fid & 7;
    const int w   = fid >> 3;               // 0..63
    const int qt  = 15 - (w >> 2);          // 15..0 (128-row tile index)
    const int bh  = xcd * 4 + (w & 3);      // 0..31
    const int b = bh >> 4, h = bh & 15;
    const int jmax = 2 * qt + 1;

    const size_t rowbase = (size_t)b * T;
    const __bf16* Kbase = qkv + 1024 + h * 64;
    const __bf16* Vbase = qkv + 2048 + h * 64;

    const int krow = tid >> 3;              // 0..63
    const int kcbs = tid & 7;
    const int kcbf = kcbs ^ (krow & 7);
    const int vrow = krow, va = kcbs;

    // ---- Q fragments (B-operand of S^T), scale folded ----
    bf16_8 aq[2][2];
    #pragma unroll
    for (int mt = 0; mt < 2; ++mt) {
        const __bf16* qrow =
            qkv + (rowbase + qt * 128 + wq * 32 + mt * 16 + l16) * 3072 + h * 64;
        aq[mt][0] = *(const bf16_8*)(qrow + quad * 8);
        aq[mt][1] = *(const bf16_8*)(qrow + 32 + quad * 8);
        #pragma unroll
        for (int u = 0; u < 8; ++u) {
            aq[mt][0][u] = (__bf16)((float)aq[mt][0][u] * 0.125f);
            aq[mt][1][u] = (__bf16)((float)aq[mt][1][u] * 0.125f);
        }
    }

    // ---- prologue: stage tile j=0 into buf 0 ----
    load16_to_lds(Kbase + (rowbase + krow) * 3072 + kcbf * 8, &Ks[wave * 512]);
    {
        bf16_8 vv = *(const bf16_8*)(Vbase + (rowbase + vrow) * 3072 + va * 8);
        int kc = vrow >> 3, kl = vrow & 7;
        #pragma unroll
        for (int u = 0; u < 8; ++u)
            Vt[(va * 8 + u) * 64 + ((kc ^ u ^ va) << 3) + kl] = vv[u];
    }

    float l_i[2] = {0.f, 0.f};
    f32_4 O[2][4];
    #pragma unroll
    for (int mt = 0; mt < 2; ++mt)
        #pragma unroll
        for (int dt = 0; dt < 4; ++dt) O[mt][dt] = f32_4{0.f, 0.f, 0.f, 0.f};

    for (int j = 0; j <= jmax; ++j) {
        const int cur = j & 1, nxt = cur ^ 1;
        __syncthreads();   // buf[cur] staged; buf[nxt] reads complete

        const bool stage = (j < jmax);
        bf16_8 vv;
        if (stage) {
            const int jn = j + 1;
            load16_to_lds(Kbase + (rowbase + jn * 64 + krow) * 3072 + kcbf * 8,
                          &Ks[nxt * 4096 + wave * 512]);
            vv = *(const bf16_8*)(Vbase + (rowbase + jn * 64 + vrow) * 3072 + va * 8);
        }

        // ---- S^T = K (Q/8)^T : A=K-frag, B=Q-frag ----
        f32_4 S[2][2];   // [mt][nt]
        #pragma unroll
        for (int nt = 0; nt < 2; ++nt) {
            int rk = wg * 32 + nt * 16 + l16;
            int rx = rk & 7;
            bf16_8 kb0 = *(const bf16_8*)&Ks[cur * 4096 + rk * 64 + ((quad ^ rx) << 3)];
            bf16_8 kb1 = *(const bf16_8*)&Ks[cur * 4096 + rk * 64 + (((quad + 4) ^ rx) << 3)];
            #pragma unroll
            for (int mt = 0; mt < 2; ++mt) {
                f32_4 zz = {0.f, 0.f, 0.f, 0.f};
                zz = __builtin_amdgcn_mfma_f32_16x16x32_bf16(kb0, aq[mt][0], zz, 0, 0, 0);
                zz = __builtin_amdgcn_mfma_f32_16x16x32_bf16(kb1, aq[mt][1], zz, 0, 0, 0);
                S[mt][nt] = zz;
            }
        }

        // ---- exp + causal mask; P^T stays in registers as x16 B-frags ----
        const bool diag = (j >= 2 * qt);
        bf16_4 bp[2][2];   // [mt][nt]
        #pragma unroll
        for (int mt = 0; mt < 2; ++mt) {
            int qg = qt * 128 + wq * 32 + mt * 16 + l16;
            #pragma unroll
            for (int nt = 0; nt < 2; ++nt) {
                #pragma unroll
                for (int rr = 0; rr < 4; ++rr) {
                    float p = __expf(S[mt][nt][rr]);
                    if (diag) {
                        int key = j * 64 + wg * 32 + nt * 16 + quad * 4 + rr;
                        if (key > qg) p = 0.f;
                    }
                    l_i[mt] += p;
                    bp[mt][nt][rr] = (__bf16)p;
                }
            }
        }

        // ---- O^T += V^T P^T  (x16 MFMAs; V^T A-frags read b64 from Vt) ----
        #pragma unroll
        for (int dt = 0; dt < 4; ++dt) {
            int d = dt * 16 + l16;
            int dsw = (d & 7) ^ ((d >> 3) & 7);
            #pragma unroll
            for (int nt = 0; nt < 2; ++nt) {
                int kc16 = wg * 2 + nt;
                int chv = (kc16 * 2 + (quad >> 1)) ^ dsw;
                bf16_4 vaf = *(const bf16_4*)&Vt[cur * 4096 + d * 64 + chv * 8 + (quad & 1) * 4];
                #pragma unroll
                for (int mt = 0; mt < 2; ++mt)
                    O[mt][dt] = mfma16x16x16(vaf, bp[mt][nt], O[mt][dt]);
            }
        }

        // ---- late: V transpose for next tile ----
        if (stage) {
            int kc = vrow >> 3, kl = vrow & 7;
            #pragma unroll
            for (int u = 0; u < 8; ++u)
                Vt[nxt * 4096 + (va * 8 + u) * 64 + ((kc ^ u ^ va) << 3) + kl] = vv[u];
        }
    }

    // ---- reduce l across quads (2 shuffles), merge wg halves via LDS ----
    float lw[2];
    #pragma unroll
    for (int mt = 0; mt < 2; ++mt) {
        float v = l_i[mt];
        v += __shfl_xor(v, 16, 64);
        v += __shfl_xor(v, 32, 64);
        lw[mt] = v;
    }
    __syncthreads();   // all Ks/Vt reads done before Om aliases the pool
    if (wg == 1) {
        #pragma unroll
        for (int mt = 0; mt < 2; ++mt) {
            #pragma unroll
            for (int dt = 0; dt < 4; ++dt)
                *(f32_4*)&Om[(wq * 32 + mt * 16 + l16) * 68 + dt * 16 + quad * 4] = O[mt][dt];
            if (quad == 0) Lm[wq * 32 + mt * 16 + l16] = lw[mt];
        }
    }
    __syncthreads();
    if (wg == 0) {
        #pragma unroll
        for (int mt = 0; mt < 2; ++mt) {
            float inv = 1.f / (lw[mt] + Lm[wq * 32 + mt * 16 + l16]);
            int q = qt * 128 + wq * 32 + mt * 16 + l16;
            #pragma unroll
            for (int dt = 0; dt < 4; ++dt) {
                f32_4 o2 = *(const f32_4*)&Om[(wq * 32 + mt * 16 + l16) * 68 + dt * 16 + quad * 4];
                bf16_4 ov;
                #pragma unroll
                for (int rr = 0; rr < 4; ++rr)
                    ov[rr] = (__bf16)((O[mt][dt][rr] + o2[rr]) * inv);
                *(bf16_4*)(out + (rowbase + q) * 1024 + h * 64 + dt * 16 + quad * 4) = ov;
            }
        }
    }
}

// ---------------- launch ----------------
extern "C" void kernel_launch(void* const* d_in, const int* in_sizes, int n_in,
                              void* d_out, int out_size, void* d_ws, size_t ws_size,
                              hipStream_t stream)
{
    constexpr int Bc = 2, Tc = 2048, Dc = 1024;
    constexpr int M  = Bc * Tc;
    constexpr int N1 = 3 * Dc;

    const float* x     = (const float*)d_in[0];
    const float* Wqkv  = (const float*)d_in[1];
    const float* bqkv  = (const float*)d_in[2];
    const float* Wproj = (const float*)d_in[3];
    const float* bproj = (const float*)d_in[4];
    float* outp = (float*)d_out;

    __bf16* xb     = (__bf16*)d_ws;
    __bf16* wqkvb  = xb     + (size_t)M * Dc;
    __bf16* wprojb = wqkvb  + (size_t)N1 * Dc;
    __bf16* qkvb   = wprojb + (size_t)Dc * Dc;
    __bf16* attnb  = qkvb   + (size_t)M * N1;

    {
        int na4 = M * Dc / 4, nb4 = N1 * Dc / 4, nc4 = Dc * Dc / 4;
        int n4 = na4 + nb4 + nc4;
        cvt_all<<<(n4 + 255) / 256, 256, 0, stream>>>(x, Wqkv, Wproj, xb, na4, nb4, nc4);
    }

    gemm_bt<1, 128><<<dim3(N1 / 128, M / BM), 256, 0, stream>>>(
        xb, wqkvb, bqkv, qkvb, nullptr, M, N1, Dc);

    attn_kernel<<<dim3(512), 512, 0, stream>>>(qkvb, attnb);

    gemm_bt<0, 64><<<dim3(Dc / 64, M / BM), 256, 0, stream>>>(
        attnb, wprojb, bproj, nullptr, outp, M, Dc, Dc);
}

// Round 7
// 170.227 us; speedup vs baseline: 1.0531x; 1.0531x over previous
//
#include <hip/hip_runtime.h>

// ---------------- types ----------------
typedef __bf16 bf16_8 __attribute__((ext_vector_type(8)));
typedef __bf16 bf16_4 __attribute__((ext_vector_type(4)));
typedef float  f32_4  __attribute__((ext_vector_type(4)));
typedef short  s16x4  __attribute__((ext_vector_type(4)));

typedef __attribute__((address_space(1))) const void* as1_cvp;
typedef __attribute__((address_space(3))) void*       as3_vp;

__device__ __forceinline__ void load16_to_lds(const void* g, void* l) {
    __builtin_amdgcn_global_load_lds((as1_cvp)g, (as3_vp)l, 16, 0, 0);
}

__device__ __forceinline__ f32_4 mfma16x16x16(bf16_4 a, bf16_4 b, f32_4 c) {
#if __has_builtin(__builtin_amdgcn_mfma_f32_16x16x16_bf16)
    return __builtin_amdgcn_mfma_f32_16x16x16_bf16(a, b, c, 0, 0, 0);
#else
    return __builtin_amdgcn_mfma_f32_16x16x16bf16_1k(
        __builtin_bit_cast(s16x4, a), __builtin_bit_cast(s16x4, b), c, 0, 0, 0);
#endif
}

// ---------------- fused fp32 -> bf16 convert (x | Wqkv | Wproj) ----------------
__global__ __launch_bounds__(256) void cvt_all(
    const float* __restrict__ a, const float* __restrict__ b,
    const float* __restrict__ c, __bf16* __restrict__ out,
    int na4, int nb4, int nc4)
{
    int i = blockIdx.x * 256 + threadIdx.x;
    if (i >= na4 + nb4 + nc4) return;
    float4 f;
    if (i < na4)            f = ((const float4*)a)[i];
    else if (i < na4 + nb4) f = ((const float4*)b)[i - na4];
    else                    f = ((const float4*)c)[i - na4 - nb4];
    bf16_4 v = { (__bf16)f.x, (__bf16)f.y, (__bf16)f.z, (__bf16)f.w };
    ((bf16_4*)out)[i] = v;
}

// ---------------- bf16 GEMM: C[M,N] = A[M,K] * B[N,K]^T + bias ----------------
// QKV==1: N=3072 logical; cols <2048 (Q|K) stored to Cb with row stride ldc=2048;
// cols >=2048 (V) stored TRANSPOSED to Vtb as [b][h*64+d][t] directly from
// accumulators (the 4 acc elems per lane are contiguous t in V^T -> b64 stores).
#define BM 128

template<int OUT_BF16, int BN_, int QKV>
__global__ __launch_bounds__(256) void gemm_bt(
    const __bf16* __restrict__ A,   // [M,K]
    const __bf16* __restrict__ B,   // [N,K]
    const float*  __restrict__ bias,// [N] or nullptr
    __bf16* __restrict__ Cb, float* __restrict__ Cf,
    __bf16* __restrict__ Vtb,
    int M, int N, int K, int ldc)
{
    constexpr int NT   = BN_ / 32;
    constexpr int CSTR = BN_ + (OUT_BF16 ? 8 : 4);
    __shared__ __align__(16) char smem[35840];
    __bf16* As = (__bf16*)smem;          // [128][64]
    __bf16* Bs = As + 128 * 64;          // [BN_][64]

    const int tid  = threadIdx.x;
    const int wave = tid >> 6;
    const int lane = tid & 63;
    const int wm = wave >> 1, wn = wave & 1;
    const int quad = lane >> 4, l16 = lane & 15;
    const int bm = blockIdx.y * BM, bn = blockIdx.x * BN_;

    const int r0 = tid >> 3;
    const int ch = tid & 7;
    const int cs = (ch ^ (r0 & 7)) * 8;

    f32_4 acc[4][NT];
    #pragma unroll
    for (int i = 0; i < 4; ++i)
        #pragma unroll
        for (int j = 0; j < NT; ++j)
            acc[i][j] = f32_4{0.f, 0.f, 0.f, 0.f};

    for (int k0 = 0; k0 < K; k0 += 64) {
        __syncthreads();
        #pragma unroll
        for (int p = 0; p < 4; ++p) {
            int row = p * 32 + r0;
            load16_to_lds(A + (size_t)(bm + row) * K + k0 + cs,
                          &As[(p * 32 + wave * 8) * 64]);
        }
        #pragma unroll
        for (int p = 0; p < BN_ / 32; ++p) {
            int row = p * 32 + r0;
            load16_to_lds(B + (size_t)(bn + row) * K + k0 + cs,
                          &Bs[(p * 32 + wave * 8) * 64]);
        }
        __syncthreads();

        #pragma unroll
        for (int h = 0; h < 2; ++h) {
            const int sl = ((quad + h * 4) ^ (l16 & 7)) * 8;
            bf16_8 af[4], bfr[NT];
            #pragma unroll
            for (int mt = 0; mt < 4; ++mt)
                af[mt] = *(const bf16_8*)&As[(wm * 64 + mt * 16 + l16) * 64 + sl];
            #pragma unroll
            for (int nt = 0; nt < NT; ++nt)
                bfr[nt] = *(const bf16_8*)&Bs[(wn * (BN_/2) + nt * 16 + l16) * 64 + sl];
            #pragma unroll
            for (int mt = 0; mt < 4; ++mt)
                #pragma unroll
                for (int nt = 0; nt < NT; ++nt)
                    acc[mt][nt] = __builtin_amdgcn_mfma_f32_16x16x32_bf16(
                        af[mt], bfr[nt], acc[mt][nt], 0, 0, 0);
        }
    }

    if (QKV && bn >= 2048) {
        // ---- V tile: store transposed directly (V^T[b][h*64+d][t]) ----
        const int b_ = bm >> 11;
        const int t0 = (bm & 2047) + wm * 64;
        #pragma unroll
        for (int nt = 0; nt < NT; ++nt) {
            int vrow = (bn - 2048) + wn * (BN_/2) + nt * 16 + l16;   // h*64+d
            float bv = bias ? bias[2048 + vrow] : 0.f;
            #pragma unroll
            for (int mt = 0; mt < 4; ++mt) {
                bf16_4 ov;
                #pragma unroll
                for (int r = 0; r < 4; ++r)
                    ov[r] = (__bf16)(acc[mt][nt][r] + bv);
                *(bf16_4*)(Vtb + ((size_t)b_ * 1024 + vrow) * 2048
                           + t0 + mt * 16 + quad * 4) = ov;
            }
        }
        return;
    }

    __syncthreads();

    if (OUT_BF16) {
        __bf16* Cs = (__bf16*)smem;
        #pragma unroll
        for (int mt = 0; mt < 4; ++mt)
            #pragma unroll
            for (int nt = 0; nt < NT; ++nt) {
                int col = wn * (BN_/2) + nt * 16 + l16;
                float bv = bias ? bias[bn + col] : 0.f;
                #pragma unroll
                for (int r = 0; r < 4; ++r)
                    Cs[(wm * 64 + mt * 16 + quad * 4 + r) * CSTR + col] =
                        (__bf16)(acc[mt][nt][r] + bv);
            }
        __syncthreads();
        const int rr = tid >> 4, cc = (tid & 15) * 8;
        #pragma unroll
        for (int p = 0; p < 8; ++p) {
            int row = p * 16 + rr;
            bf16_8 v = *(const bf16_8*)&Cs[row * CSTR + cc];
            *(bf16_8*)(Cb + (size_t)(bm + row) * ldc + bn + cc) = v;
        }
    } else {
        float* Cs = (float*)smem;
        #pragma unroll
        for (int mt = 0; mt < 4; ++mt)
            #pragma unroll
            for (int nt = 0; nt < NT; ++nt) {
                int col = wn * (BN_/2) + nt * 16 + l16;
                float bv = bias ? bias[bn + col] : 0.f;
                #pragma unroll
                for (int r = 0; r < 4; ++r)
                    Cs[(wm * 64 + mt * 16 + quad * 4 + r) * CSTR + col] =
                        acc[mt][nt][r] + bv;
            }
        __syncthreads();
        const int rr = tid >> 4, cc = (tid & 15) * 4;
        #pragma unroll
        for (int p = 0; p < 8; ++p) {
            int row = p * 16 + rr;
            float4 v = *(const float4*)&Cs[row * CSTR + cc];
            *(float4*)(Cf + (size_t)(bm + row) * ldc + bn + cc) = v;
        }
    }
}

// ---------------- causal flash attention v7 ----------------
// Transposed-score formulation (P^T in registers, no P LDS roundtrip).
// qk: [B*T, 2048] bf16 (Q|K, each 1024), vt: [B*16, 64, 2048] bf16 (V^T).
// Both K and V^T staged via swizzled async global_load_lds (double-buffered):
// zero in-wave transpose work. 8 waves: wq owns 32 q-rows, wg splits 64 keys.
// Balanced 2-blocks/CU pairing: fid<256 -> qt=(w>>2)+8, else qt=7-(w>>2)
// -> every CU hosts (k+8, 7-k): uniformly 34 j-iterations.
__global__ __launch_bounds__(512, 4) void attn_kernel(
    const __bf16* __restrict__ qk, const __bf16* __restrict__ vt,
    __bf16* __restrict__ out)
{
    constexpr int T = 2048;
    __shared__ __align__(16) char pool[35328];
    __bf16* Ks = (__bf16*)pool;             // [2][64*64] chunk-swizzled
    __bf16* Vt = (__bf16*)(pool + 16384);   // [2][64*64] chunk-swizzled (rows=d)
    float*  Om = (float*)pool;              // alias: [4][32][68] (34816 B)
    float*  Lm = (float*)(pool + 34816);    // [4][32]

    const int tid  = threadIdx.x;
    const int wave = tid >> 6;
    const int lane = tid & 63;
    const int wg = wave >> 2, wq = wave & 3;
    const int quad = lane >> 4, l16 = lane & 15;

    const int fid  = blockIdx.x;            // 0..511
    const int xcd  = fid & 7;
    const int half = fid >> 8;
    const int w    = (fid >> 3) & 31;       // 0..31
    const int qt   = half ? (7 - (w >> 2)) : ((w >> 2) + 8);
    const int bh   = xcd * 4 + (w & 3);     // 0..31
    const int b = bh >> 4, h = bh & 15;
    const int jmax = 2 * qt + 1;

    const size_t rowbase = (size_t)b * T;
    const __bf16* Kbase = qk + 1024 + h * 64;            // row stride 2048
    const __bf16* Vbase = vt + (size_t)bh * 64 * 2048;   // [d][t]

    const int srow = tid >> 3;              // 0..63
    const int sch  = tid & 7;
    const int schf = sch ^ (srow & 7);      // fetched chunk (swizzle)

    // ---- Q fragments (B-operand of S^T), scale folded ----
    bf16_8 aq[2][2];
    #pragma unroll
    for (int mt = 0; mt < 2; ++mt) {
        const __bf16* qrow =
            qk + (rowbase + qt * 128 + wq * 32 + mt * 16 + l16) * 2048 + h * 64;
        aq[mt][0] = *(const bf16_8*)(qrow + quad * 8);
        aq[mt][1] = *(const bf16_8*)(qrow + 32 + quad * 8);
        #pragma unroll
        for (int u = 0; u < 8; ++u) {
            aq[mt][0][u] = (__bf16)((float)aq[mt][0][u] * 0.125f);
            aq[mt][1][u] = (__bf16)((float)aq[mt][1][u] * 0.125f);
        }
    }

    // ---- prologue: stage tile j=0 into buf 0 ----
    load16_to_lds(Kbase + (rowbase + srow) * 2048 + schf * 8, &Ks[wave * 512]);
    load16_to_lds(Vbase + (size_t)srow * 2048 + schf * 8,     &Vt[wave * 512]);

    float l_i[2] = {0.f, 0.f};
    f32_4 O[2][4];
    #pragma unroll
    for (int mt = 0; mt < 2; ++mt)
        #pragma unroll
        for (int dt = 0; dt < 4; ++dt) O[mt][dt] = f32_4{0.f, 0.f, 0.f, 0.f};

    for (int j = 0; j <= jmax; ++j) {
        const int cur = j & 1, nxt = cur ^ 1;
        __syncthreads();   // buf[cur] staged; buf[nxt] reads complete

        if (j < jmax) {
            const int jn = j + 1;
            load16_to_lds(Kbase + (rowbase + jn * 64 + srow) * 2048 + schf * 8,
                          &Ks[nxt * 4096 + wave * 512]);
            load16_to_lds(Vbase + (size_t)srow * 2048 + jn * 64 + schf * 8,
                          &Vt[nxt * 4096 + wave * 512]);
        }

        // ---- S^T = K (Q/8)^T : A=K-frag, B=Q-frag ----
        f32_4 S[2][2];   // [mt][nt]
        #pragma unroll
        for (int nt = 0; nt < 2; ++nt) {
            int rk = wg * 32 + nt * 16 + l16;
            int rx = rk & 7;
            bf16_8 kb0 = *(const bf16_8*)&Ks[cur * 4096 + rk * 64 + ((quad ^ rx) << 3)];
            bf16_8 kb1 = *(const bf16_8*)&Ks[cur * 4096 + rk * 64 + (((quad + 4) ^ rx) << 3)];
            #pragma unroll
            for (int mt = 0; mt < 2; ++mt) {
                f32_4 zz = {0.f, 0.f, 0.f, 0.f};
                zz = __builtin_amdgcn_mfma_f32_16x16x32_bf16(kb0, aq[mt][0], zz, 0, 0, 0);
                zz = __builtin_amdgcn_mfma_f32_16x16x32_bf16(kb1, aq[mt][1], zz, 0, 0, 0);
                S[mt][nt] = zz;
            }
        }

        // ---- exp + causal mask; P^T stays in registers as x16 B-frags ----
        const bool diag = (j >= 2 * qt);
        bf16_4 bp[2][2];   // [mt][nt]
        #pragma unroll
        for (int mt = 0; mt < 2; ++mt) {
            int qg = qt * 128 + wq * 32 + mt * 16 + l16;
            #pragma unroll
            for (int nt = 0; nt < 2; ++nt) {
                #pragma unroll
                for (int rr = 0; rr < 4; ++rr) {
                    float p = __expf(S[mt][nt][rr]);
                    if (diag) {
                        int key = j * 64 + wg * 32 + nt * 16 + quad * 4 + rr;
                        if (key > qg) p = 0.f;
                    }
                    l_i[mt] += p;
                    bp[mt][nt][rr] = (__bf16)p;
                }
            }
        }

        // ---- O^T += V^T P^T  (x16 MFMAs; A-frags b64 from swizzled Vt) ----
        #pragma unroll
        for (int dt = 0; dt < 4; ++dt) {
            int d = dt * 16 + l16;
            int dsw = d & 7;
            #pragma unroll
            for (int nt = 0; nt < 2; ++nt) {
                int chv = (wg * 4 + nt * 2 + (quad >> 1)) ^ dsw;
                bf16_4 vaf = *(const bf16_4*)&Vt[cur * 4096 + d * 64 + chv * 8 + (quad & 1) * 4];
                #pragma unroll
                for (int mt = 0; mt < 2; ++mt)
                    O[mt][dt] = mfma16x16x16(vaf, bp[mt][nt], O[mt][dt]);
            }
        }
    }

    // ---- reduce l across quads, merge wg halves via LDS ----
    float lw[2];
    #pragma unroll
    for (int mt = 0; mt < 2; ++mt) {
        float v = l_i[mt];
        v += __shfl_xor(v, 16, 64);
        v += __shfl_xor(v, 32, 64);
        lw[mt] = v;
    }
    __syncthreads();   // all Ks/Vt reads done before Om aliases the pool
    if (wg == 1) {
        #pragma unroll
        for (int mt = 0; mt < 2; ++mt) {
            #pragma unroll
            for (int dt = 0; dt < 4; ++dt)
                *(f32_4*)&Om[(wq * 32 + mt * 16 + l16) * 68 + dt * 16 + quad * 4] = O[mt][dt];
            if (quad == 0) Lm[wq * 32 + mt * 16 + l16] = lw[mt];
        }
    }
    __syncthreads();
    if (wg == 0) {
        #pragma unroll
        for (int mt = 0; mt < 2; ++mt) {
            float inv = 1.f / (lw[mt] + Lm[wq * 32 + mt * 16 + l16]);
            int q = qt * 128 + wq * 32 + mt * 16 + l16;
            #pragma unroll
            for (int dt = 0; dt < 4; ++dt) {
                f32_4 o2 = *(const f32_4*)&Om[(wq * 32 + mt * 16 + l16) * 68 + dt * 16 + quad * 4];
                bf16_4 ov;
                #pragma unroll
                for (int rr = 0; rr < 4; ++rr)
                    ov[rr] = (__bf16)((O[mt][dt][rr] + o2[rr]) * inv);
                *(bf16_4*)(out + (rowbase + q) * 1024 + h * 64 + dt * 16 + quad * 4) = ov;
            }
        }
    }
}

// ---------------- launch ----------------
extern "C" void kernel_launch(void* const* d_in, const int* in_sizes, int n_in,
                              void* d_out, int out_size, void* d_ws, size_t ws_size,
                              hipStream_t stream)
{
    constexpr int Bc = 2, Tc = 2048, Dc = 1024;
    constexpr int M  = Bc * Tc;
    constexpr int N1 = 3 * Dc;

    const float* x     = (const float*)d_in[0];
    const float* Wqkv  = (const float*)d_in[1];
    const float* bqkv  = (const float*)d_in[2];
    const float* Wproj = (const float*)d_in[3];
    const float* bproj = (const float*)d_in[4];
    float* outp = (float*)d_out;

    __bf16* xb     = (__bf16*)d_ws;                        // 4096*1024
    __bf16* wqkvb  = xb     + (size_t)M * Dc;              // 3072*1024
    __bf16* wprojb = wqkvb  + (size_t)N1 * Dc;             // 1024*1024
    __bf16* qkb    = wprojb + (size_t)Dc * Dc;             // 4096*2048 (Q|K)
    __bf16* vtb    = qkb    + (size_t)M * 2048;            // 2*1024*2048 (V^T)
    __bf16* attnb  = vtb    + (size_t)Bc * 1024 * 2048;    // 4096*1024

    {
        int na4 = M * Dc / 4, nb4 = N1 * Dc / 4, nc4 = Dc * Dc / 4;
        int n4 = na4 + nb4 + nc4;
        cvt_all<<<(n4 + 255) / 256, 256, 0, stream>>>(x, Wqkv, Wproj, xb, na4, nb4, nc4);
    }

    gemm_bt<1, 128, 1><<<dim3(N1 / 128, M / BM), 256, 0, stream>>>(
        xb, wqkvb, bqkv, qkb, nullptr, vtb, M, N1, Dc, 2048);

    attn_kernel<<<dim3(512), 512, 0, stream>>>(qkb, vtb, attnb);

    gemm_bt<0, 64, 0><<<dim3(Dc / 64, M / BM), 256, 0, stream>>>(
        attnb, wprojb, bproj, nullptr, outp, nullptr, M, Dc, Dc, Dc);
}